// Round 6
// baseline (159.243 us; speedup 1.0000x reference)
//
#include <hip/hip_runtime.h>
#include <stdint.h>

#define BB 64
#define TT 2048
#define EE 1024
#define ST 32                 // t-splits per batch row (block level)
#define TBLK 64               // t per block
#define BG 2                  // b's per block
#define NBG (BB / BG)         // 32 b-groups
#define NB 16                 // 2-row batches per wave (32 rows/wave)
#define PP 64                 // partials per b  (ST * 2 halves)

// ws float offsets
#define M_OFF 0
#define L_OFF (BB * PP)
#define O_OFF (2 * BB * PP)

// One 2-row batch: issue next batch's 8 loads into NXT, dot CUR vs wf,
// two interleaved 6-stage shfl reduces, branch-free online-softmax update.
#define BATCH(bt, CUR, NXT)                                                     \
  do {                                                                          \
    if ((bt) + 1 < NB) {                                                        \
      const float4* np = xw4 + (size_t)((bt) + 1) * 2 * 256;                    \
      _Pragma("unroll")                                                         \
      for (int k = 0; k < 4; ++k) NXT[k] = np[lane + 64 * k];                   \
      _Pragma("unroll")                                                         \
      for (int k = 0; k < 4; ++k) NXT[4 + k] = np[256 + lane + 64 * k];         \
    }                                                                           \
    float s0 = 0.f, s1 = 0.f;                                                   \
    _Pragma("unroll")                                                           \
    for (int k = 0; k < 4; ++k) {                                               \
      s0 += CUR[k].x * wf[k].x + CUR[k].y * wf[k].y +                           \
            CUR[k].z * wf[k].z + CUR[k].w * wf[k].w;                            \
      s1 += CUR[4 + k].x * wf[k].x + CUR[4 + k].y * wf[k].y +                   \
            CUR[4 + k].z * wf[k].z + CUR[4 + k].w * wf[k].w;                    \
    }                                                                           \
    _Pragma("unroll")                                                           \
    for (int off = 32; off >= 1; off >>= 1) {                                   \
      s0 += __shfl_xor(s0, off, 64);                                            \
      s1 += __shfl_xor(s1, off, 64);                                            \
    }                                                                           \
    const float et0 = s0 + cu_row[2 * (bt)];                                    \
    const float et1 = s1 + cu_row[2 * (bt) + 1];                                \
    const float mn = fmaxf(m, fmaxf(et0, et1));                                 \
    const float rr = __expf(m - mn);                                            \
    const float p0 = __expf(et0 - mn), p1 = __expf(et1 - mn);                   \
    m = mn;                                                                     \
    l = l * rr + p0 + p1;                                                       \
    _Pragma("unroll")                                                           \
    for (int k = 0; k < 4; ++k) {                                               \
      o[k].x = o[k].x * rr + p0 * CUR[k].x + p1 * CUR[4 + k].x;                 \
      o[k].y = o[k].y * rr + p0 * CUR[k].y + p1 * CUR[4 + k].y;                 \
      o[k].z = o[k].z * rr + p0 * CUR[k].z + p1 * CUR[4 + k].z;                 \
      o[k].w = o[k].w * rr + p0 * CUR[k].w + p1 * CUR[4 + k].w;                 \
    }                                                                           \
  } while (0)

// Fused single-pass. Block = (b-pair, ts): cooperative cu prologue, then each
// wave streams its own (b, 32-row half) fully autonomously — full E per wave,
// no barriers, no LDS in the stream loop. 1024 blocks -> 4/CU, 16 waves/CU.
__global__ __launch_bounds__(256, 4) void k_fused(
    const float* __restrict__ x, const float* __restrict__ c,
    const float* __restrict__ W, const float* __restrict__ bvec,
    const float* __restrict__ U,
    float* __restrict__ m_part, float* __restrict__ l_part,
    float* __restrict__ o_part)
{
    const int bg   = blockIdx.x >> 5;   // blockIdx = bg*ST + ts (ts mod 8 -> same XCD shares U slice)
    const int ts   = blockIdx.x & 31;
    const int b0   = bg * BG;
    const int t0   = ts * TBLK;
    const int tid  = threadIdx.x;
    const int wu   = __builtin_amdgcn_readfirstlane(tid >> 6);  // wave id, uniform
    const int lane = tid & 63;

    __shared__ float cu_s[BG][TBLK];     // 512 B
    __shared__ float pcu[4][BG][TBLK];   // 2 KB prologue exchange

    // wave's stream span: b = b0 + (wu>>1), t half = (wu&1)*32
    const int bl_w = wu >> 1;
    const int th_w = wu & 1;
    const float4* xw4 = (const float4*)x +
                        ((size_t)(b0 + bl_w) * TT + t0 + th_w * 32) * 256;

    // preload batch 0 (8 x float4 in flight during prologue)
    float4 XA[8], XB[8];
    #pragma unroll
    for (int k = 0; k < 4; ++k) XA[k] = xw4[lane + 64 * k];
    #pragma unroll
    for (int k = 0; k < 4; ++k) XA[4 + k] = xw4[256 + lane + 64 * k];

    // ---- prologue: cu_s[j][t] = bvec[t0+t] + c[b0+j,:]·U[:,t0+t], j=0,1 ----
    // wave wu covers e-quarter [wu*256, wu*256+256); lane = t; U coalesced 256B.
    {
        const float* cb = c + (size_t)b0 * EE + (wu << 8);          // uniform -> s_load
        const float* Ub = U + ((size_t)(wu << 8)) * TT + t0 + lane; // coalesced
        float a0 = 0.f, a1 = 0.f;
        #pragma unroll 8
        for (int e = 0; e < 256; ++e) {
            const float u = Ub[(size_t)e * TT];
            a0 = fmaf(cb[e], u, a0);
            a1 = fmaf(cb[EE + e], u, a1);
        }
        pcu[wu][0][lane] = a0;
        pcu[wu][1][lane] = a1;
    }
    __syncthreads();
    if (tid < BG * TBLK) {
        const int j = tid >> 6, t = tid & 63;
        cu_s[j][t] = bvec[t0 + t] + pcu[0][j][t] + pcu[1][j][t] + pcu[2][j][t] + pcu[3][j][t];
    }
    __syncthreads();

    const float* cu_row = &cu_s[bl_w][th_w * 32];

    // full-E W fragment: float4 index lane+64k covers e = 4*lane + 256*k
    float4 wf[4];
    #pragma unroll
    for (int k = 0; k < 4; ++k) wf[k] = ((const float4*)W)[lane + 64 * k];

    float  m = -1e30f, l = 0.f;
    float4 o[4];
    #pragma unroll
    for (int k = 0; k < 4; ++k) o[k] = make_float4(0.f, 0.f, 0.f, 0.f);

    // ---- wave-autonomous stream: 16 batches of 2 rows, no barriers ----
    for (int bt = 0; bt < NB; bt += 2) {
        BATCH(bt,     XA, XB);
        BATCH(bt + 1, XB, XA);
    }

    // partial for (b, ts, half): coalesced full-row write
    const int pi = (b0 + bl_w) * PP + ts * 2 + th_w;
    #pragma unroll
    for (int k = 0; k < 4; ++k)
        ((float4*)o_part)[(size_t)pi * 256 + lane + 64 * k] = o[k];
    if (lane == 0) { m_part[pi] = m; l_part[pi] = l; }
}

// ---------------- merge PP partials per batch row ----------------
__global__ __launch_bounds__(256) void k_merge(const float* __restrict__ m_part,
                                               const float* __restrict__ l_part,
                                               const float* __restrict__ o_part,
                                               float* __restrict__ out) {
    const int b = blockIdx.x;
    const int tid = threadIdx.x;

    float M = -1e30f;
    #pragma unroll 8
    for (int p = 0; p < PP; ++p) M = fmaxf(M, m_part[b * PP + p]);

    float L = 0.f;
    float4 acc = make_float4(0.f, 0.f, 0.f, 0.f);
    for (int p = 0; p < PP; ++p) {
        const int pi = b * PP + p;
        const float r = __expf(m_part[pi] - M);
        L += r * l_part[pi];
        const float4 v = ((const float4*)(o_part + (size_t)pi * EE))[tid];
        acc.x += r * v.x; acc.y += r * v.y; acc.z += r * v.z; acc.w += r * v.w;
    }
    const float inv = 1.f / L;
    acc.x *= inv; acc.y *= inv; acc.z *= inv; acc.w *= inv;
    ((float4*)(out + (size_t)b * EE))[tid] = acc;
}

extern "C" void kernel_launch(void* const* d_in, const int* in_sizes, int n_in,
                              void* d_out, int out_size, void* d_ws, size_t ws_size,
                              hipStream_t stream) {
    const float* x    = (const float*)d_in[0];  // (B,T,E)
    const float* c    = (const float*)d_in[1];  // (B,E)
    const float* W    = (const float*)d_in[2];  // (E,1)
    const float* bvec = (const float*)d_in[3];  // (T,1)
    const float* U    = (const float*)d_in[4];  // (E,T)
    float* out = (float*)d_out;                 // (B,E)

    float* ws     = (float*)d_ws;
    float* m_part = ws + M_OFF;
    float* l_part = ws + L_OFF;
    float* o_part = ws + O_OFF;

    k_fused<<<NBG * ST, 256, 0, stream>>>(x, c, W, bvec, U, m_part, l_part, o_part);
    k_merge<<<BB, 256, 0, stream>>>(m_part, l_part, o_part, out);
}